// Round 1
// baseline (783.602 us; speedup 1.0000x reference)
//
#include <hip/hip_runtime.h>
#include <math.h>

#define NN 40000
#define NE 640000
#define DD 128
#define NL 3

__device__ __forceinline__ float sigmoidf_(float x) {
    return 1.0f / (1.0f + __expf(-x));
}

// ---------------------------------------------------------------------------
// Edge preprocessing: detect int64 vs int32 edge_index, normalize to int32
// ---------------------------------------------------------------------------
__global__ void detect_kernel(const int* __restrict__ ei, int* __restrict__ flag) {
    if (threadIdx.x == 0) {
        // If edge_index is int64 (little-endian), the high 32-bit words of the
        // first 32 values are all zero (indices < 40000). For int32 data these
        // slots are random edge values — all-zero is impossible in practice.
        int is64 = 1;
        for (int e = 0; e < 32; ++e) {
            if (ei[2 * e + 1] != 0) { is64 = 0; break; }
        }
        *flag = is64;
    }
}

__global__ void convert_kernel(const int* __restrict__ ei, const int* __restrict__ flag,
                               int* __restrict__ srcs, int* __restrict__ dsts) {
    int e = blockIdx.x * blockDim.x + threadIdx.x;
    if (e >= NE) return;
    if (*flag) {
        srcs[e] = ei[2 * e];
        dsts[e] = ei[2 * (NE + e)];
    } else {
        srcs[e] = ei[e];
        dsts[e] = ei[NE + e];
    }
}

__global__ void zero_kernel(int* __restrict__ p, int n) {
    int i = blockIdx.x * blockDim.x + threadIdx.x;
    if (i < n) p[i] = 0;
}

__global__ void hist_kernel(const int* __restrict__ dsts, int* __restrict__ count) {
    int e = blockIdx.x * blockDim.x + threadIdx.x;
    if (e >= NE) return;
    atomicAdd(&count[dsts[e]], 1);
}

__global__ __launch_bounds__(1024) void scan_kernel(const int* __restrict__ count,
                                                    int* __restrict__ row_ptr,
                                                    int* __restrict__ cursor) {
    __shared__ int part[1024];
    int t = threadIdx.x;
    int b = t * 40;
    int e = min(b + 40, NN);
    int s = 0;
    for (int i = b; i < e; ++i) s += count[i];
    part[t] = s;
    __syncthreads();
    for (int off = 1; off < 1024; off <<= 1) {
        int v = 0;
        if (t >= off) v = part[t - off];
        __syncthreads();
        part[t] += v;
        __syncthreads();
    }
    int run = part[t] - s;  // exclusive prefix
    for (int i = b; i < e; ++i) {
        row_ptr[i] = run;
        cursor[i] = run;
        run += count[i];
    }
    if (t == 1023) row_ptr[NN] = part[1023];
}

__global__ void scatter_kernel(const int* __restrict__ srcs, const int* __restrict__ dsts,
                               int* __restrict__ cursor, int* __restrict__ csr_src) {
    int e = blockIdx.x * blockDim.x + threadIdx.x;
    if (e >= NE) return;
    int i = dsts[e];
    int pos = atomicAdd(&cursor[i], 1);
    csr_src[pos] = srcs[e];
}

// ---------------------------------------------------------------------------
// Fused 4-way GEMM: y[i][m][d] = sum_c in[i][c] * W_m[d][c] + b_m[d]
// m = 0:k 1:q 2:v 3:skip (no bias). Tile: 64 rows x 128 cols per block.
// ---------------------------------------------------------------------------
__global__ __launch_bounds__(256) void gemm4_kernel(
    const float* __restrict__ in,
    const float* __restrict__ Wk, const float* __restrict__ bk,
    const float* __restrict__ Wq, const float* __restrict__ bq,
    const float* __restrict__ Wv, const float* __restrict__ bv,
    const float* __restrict__ Ws,
    float* __restrict__ y, int layer) {
    const int m = blockIdx.y;
    const float* W;
    const float* b;
    switch (m) {
        case 0:  W = Wk + layer * DD * DD; b = bk + layer * DD; break;
        case 1:  W = Wq + layer * DD * DD; b = bq + layer * DD; break;
        case 2:  W = Wv + layer * DD * DD; b = bv + layer * DD; break;
        default: W = Ws + layer * DD * DD; b = nullptr;         break;
    }
    const int row0 = blockIdx.x * 64;  // NN % 64 == 0 -> no bounds checks

    __shared__ float xs[64][36];    // +pad, 36*4 = 144B row stride (16B aligned)
    __shared__ float wsl[128][36];

    const int t = threadIdx.x;
    const int tx = t & 15;
    const int ty = t >> 4;

    float acc[4][8];
#pragma unroll
    for (int i = 0; i < 4; ++i)
#pragma unroll
        for (int j = 0; j < 8; ++j) acc[i][j] = 0.f;

    for (int kk = 0; kk < DD; kk += 32) {
        // stage x tile: 64x32 f32 = 512 float4, 2 per thread
#pragma unroll
        for (int p = 0; p < 2; ++p) {
            int idx = t + p * 256;
            int r = idx >> 3;
            int k4 = idx & 7;
            float4 xv = *(const float4*)&in[(size_t)(row0 + r) * DD + kk + k4 * 4];
            *(float4*)&xs[r][k4 * 4] = xv;
        }
        // stage W tile: 128x32 f32 = 1024 float4, 4 per thread
#pragma unroll
        for (int p = 0; p < 4; ++p) {
            int idx = t + p * 256;
            int c = idx >> 3;
            int k4 = idx & 7;
            float4 wv = *(const float4*)&W[(size_t)c * DD + kk + k4 * 4];
            *(float4*)&wsl[c][k4 * 4] = wv;
        }
        __syncthreads();
#pragma unroll
        for (int k4 = 0; k4 < 8; ++k4) {
            float4 a[4], bb[8];
#pragma unroll
            for (int i = 0; i < 4; ++i) a[i] = *(const float4*)&xs[ty + 16 * i][k4 * 4];
#pragma unroll
            for (int j = 0; j < 8; ++j) bb[j] = *(const float4*)&wsl[tx + 16 * j][k4 * 4];
#pragma unroll
            for (int i = 0; i < 4; ++i)
#pragma unroll
                for (int j = 0; j < 8; ++j) {
                    acc[i][j] += a[i].x * bb[j].x;
                    acc[i][j] += a[i].y * bb[j].y;
                    acc[i][j] += a[i].z * bb[j].z;
                    acc[i][j] += a[i].w * bb[j].w;
                }
        }
        __syncthreads();
    }

#pragma unroll
    for (int i = 0; i < 4; ++i) {
        int grow = row0 + ty + 16 * i;
#pragma unroll
        for (int j = 0; j < 8; ++j) {
            int c = tx + 16 * j;
            float o = acc[i][j] + (b ? b[c] : 0.f);
            y[((size_t)grow * 4 + m) * DD + c] = o;
        }
    }
}

// ---------------------------------------------------------------------------
// Aggregation + fused epilogue. One wave (64 lanes) per node; each lane owns
// 2 of the 128 feature dims. acc starts at skip = x@Ws^T; per edge gathers
// q[src],v[src] (coalesced 512B each) and accumulates gated messages; then
// BN(eval) -> ReLU -> row L2-norm -> skipsum (-> final L2-norm on last layer).
// ---------------------------------------------------------------------------
__global__ __launch_bounds__(256) void agg_kernel(
    const float* __restrict__ hin,
    const float* __restrict__ kqvs,   // [N][4][128]
    const int* __restrict__ row_ptr,
    const int* __restrict__ csr_src,
    const float* __restrict__ gamma, const float* __restrict__ beta,
    float* __restrict__ hout, int layer, int final_norm) {
    int wid = (blockIdx.x * blockDim.x + threadIdx.x) >> 6;
    if (wid >= NN) return;
    int lane = threadIdx.x & 63;
    int d0 = lane * 2;

    const float* base_i = kqvs + (size_t)wid * 512;
    float2 kk = *(const float2*)&base_i[d0];
    float2 acc = *(const float2*)&base_i[384 + d0];

    int s = row_ptr[wid];
    int e = row_ptr[wid + 1];
    for (int idx = s; idx < e; ++idx) {
        int j = csr_src[idx];
        const float* bj = kqvs + (size_t)j * 512 + 128;
        float2 q = *(const float2*)&bj[d0];
        float2 v = *(const float2*)&bj[128 + d0];
        acc.x += sigmoidf_(kk.x + q.x) * v.x;
        acc.y += sigmoidf_(kk.y + q.y) * v.y;
    }

    float2 g = *(const float2*)&gamma[layer * DD + d0];
    float2 bt = *(const float2*)&beta[layer * DD + d0];
    float rx = fmaxf(acc.x * g.x + bt.x, 0.f);
    float ry = fmaxf(acc.y * g.y + bt.y, 0.f);

    float ss = rx * rx + ry * ry;
#pragma unroll
    for (int m = 1; m < 64; m <<= 1) ss += __shfl_xor(ss, m);
    float inv = 1.f / fmaxf(sqrtf(ss), 1e-12f);

    float2 xin = *(const float2*)&hin[(size_t)wid * DD + d0];
    float hx = xin.x + rx * inv;
    float hy = xin.y + ry * inv;

    if (final_norm) {
        float s2 = hx * hx + hy * hy;
#pragma unroll
        for (int m = 1; m < 64; m <<= 1) s2 += __shfl_xor(s2, m);
        float inv2 = 1.f / fmaxf(sqrtf(s2), 1e-12f);
        hx *= inv2;
        hy *= inv2;
    }
    float2 o;
    o.x = hx;
    o.y = hy;
    *(float2*)&hout[(size_t)wid * DD + d0] = o;
}

// ---------------------------------------------------------------------------
extern "C" void kernel_launch(void* const* d_in, const int* in_sizes, int n_in,
                              void* d_out, int out_size, void* d_ws, size_t ws_size,
                              hipStream_t stream) {
    const float* x     = (const float*)d_in[0];
    const int*   ei    = (const int*)d_in[1];
    const float* Wk    = (const float*)d_in[2];
    const float* bk    = (const float*)d_in[3];
    const float* Wq    = (const float*)d_in[4];
    const float* bq    = (const float*)d_in[5];
    const float* Wv    = (const float*)d_in[6];
    const float* bv    = (const float*)d_in[7];
    const float* Ws    = (const float*)d_in[8];
    const float* gamma = (const float*)d_in[9];
    const float* beta  = (const float*)d_in[10];
    float* out = (float*)d_out;

    // workspace layout (floats first, 16B-aligned chunks)
    float* hb0  = (float*)d_ws;                    // [N][128]
    float* hb1  = hb0 + (size_t)NN * DD;           // [N][128]
    float* kqvs = hb1 + (size_t)NN * DD;           // [N][4][128]
    int* srcs    = (int*)(kqvs + (size_t)NN * 4 * DD);
    int* dsts    = srcs + NE;
    int* count   = dsts + NE;
    int* cursor  = count + NN;
    int* row_ptr = cursor + NN;
    int* csr_src = row_ptr + (NN + 1);
    int* flag    = csr_src + NE;

    // Build CSR (by dst) once; reused across all 3 layers.
    detect_kernel<<<1, 64, 0, stream>>>(ei, flag);
    convert_kernel<<<(NE + 255) / 256, 256, 0, stream>>>(ei, flag, srcs, dsts);
    zero_kernel<<<(NN + 255) / 256, 256, 0, stream>>>(count, NN);
    hist_kernel<<<(NE + 255) / 256, 256, 0, stream>>>(dsts, count);
    scan_kernel<<<1, 1024, 0, stream>>>(count, row_ptr, cursor);
    scatter_kernel<<<(NE + 255) / 256, 256, 0, stream>>>(srcs, dsts, cursor, csr_src);

    for (int l = 0; l < NL; ++l) {
        const float* hin = (l == 0) ? x : (l == 1 ? hb0 : hb1);
        float* hout = (l == 2) ? out : (l == 0 ? hb0 : hb1);
        gemm4_kernel<<<dim3(NN / 64, 4), 256, 0, stream>>>(hin, Wk, bk, Wq, bq, Wv, bv, Ws,
                                                           kqvs, l);
        agg_kernel<<<(NN * 64) / 256, 256, 0, stream>>>(hin, kqvs, row_ptr, csr_src, gamma,
                                                        beta, hout, l, (l == NL - 1) ? 1 : 0);
    }
}

// Round 2
// 472.538 us; speedup vs baseline: 1.6583x; 1.6583x over previous
//
#include <hip/hip_runtime.h>
#include <math.h>

#define NN 40000
#define NE 640000
#define DD 128
#define NL 3

typedef short s16x8 __attribute__((ext_vector_type(8)));
typedef float f32x4 __attribute__((ext_vector_type(4)));
typedef unsigned short ushort_t;

__device__ __forceinline__ float sigmoidf_(float x) {
    return 1.0f / (1.0f + __expf(-x));
}

// bf16 <-> f32 via bit ops (RNE)
__device__ __forceinline__ ushort_t f2bf(float f) {
    unsigned int u = __float_as_uint(f);
    u = (u + 0x7FFFu + ((u >> 16) & 1u)) >> 16;
    return (ushort_t)u;
}
__device__ __forceinline__ float bf2f(ushort_t h) {
    return __uint_as_float(((unsigned int)h) << 16);
}

// ---------------------------------------------------------------------------
// Edge preprocessing: detect int64 vs int32 edge_index, normalize to int32
// ---------------------------------------------------------------------------
__global__ void detect_kernel(const int* __restrict__ ei, int* __restrict__ flag) {
    if (threadIdx.x == 0) {
        int is64 = 1;
        for (int e = 0; e < 32; ++e) {
            if (ei[2 * e + 1] != 0) { is64 = 0; break; }
        }
        *flag = is64;
    }
}

__global__ void convert_kernel(const int* __restrict__ ei, const int* __restrict__ flag,
                               int* __restrict__ srcs, int* __restrict__ dsts) {
    int e = blockIdx.x * blockDim.x + threadIdx.x;
    if (e >= NE) return;
    if (*flag) {
        srcs[e] = ei[2 * e];
        dsts[e] = ei[2 * (NE + e)];
    } else {
        srcs[e] = ei[e];
        dsts[e] = ei[NE + e];
    }
}

__global__ void zero_kernel(int* __restrict__ p, int n) {
    int i = blockIdx.x * blockDim.x + threadIdx.x;
    if (i < n) p[i] = 0;
}

__global__ void hist_kernel(const int* __restrict__ dsts, int* __restrict__ count) {
    int e = blockIdx.x * blockDim.x + threadIdx.x;
    if (e >= NE) return;
    atomicAdd(&count[dsts[e]], 1);
}

__global__ __launch_bounds__(1024) void scan_kernel(const int* __restrict__ count,
                                                    int* __restrict__ row_ptr,
                                                    int* __restrict__ cursor) {
    __shared__ int part[1024];
    int t = threadIdx.x;
    int b = t * 40;
    int e = min(b + 40, NN);
    int s = 0;
    for (int i = b; i < e; ++i) s += count[i];
    part[t] = s;
    __syncthreads();
    for (int off = 1; off < 1024; off <<= 1) {
        int v = 0;
        if (t >= off) v = part[t - off];
        __syncthreads();
        part[t] += v;
        __syncthreads();
    }
    int run = part[t] - s;  // exclusive prefix
    for (int i = b; i < e; ++i) {
        row_ptr[i] = run;
        cursor[i] = run;
        run += count[i];
    }
    if (t == 1023) row_ptr[NN] = part[1023];
}

__global__ void scatter_kernel(const int* __restrict__ srcs, const int* __restrict__ dsts,
                               int* __restrict__ cursor, int* __restrict__ csr_src) {
    int e = blockIdx.x * blockDim.x + threadIdx.x;
    if (e >= NE) return;
    int i = dsts[e];
    int pos = atomicAdd(&cursor[i], 1);
    csr_src[pos] = srcs[e];
}

// ---------------------------------------------------------------------------
// dtype conversion: x -> bf16, weights -> bf16 packed [L][4][128][128]
// ---------------------------------------------------------------------------
__global__ void cvt_x_kernel(const float* __restrict__ x, ushort_t* __restrict__ xb) {
    int i = blockIdx.x * blockDim.x + threadIdx.x;  // one per 8 elems
    if (i >= NN * DD / 8) return;
    const float* p = x + (size_t)i * 8;
    s16x8 o;
#pragma unroll
    for (int j = 0; j < 8; ++j) o[j] = (short)f2bf(p[j]);
    *(s16x8*)&xb[(size_t)i * 8] = o;
}

__global__ void cvt_w_kernel(const float* __restrict__ Wk, const float* __restrict__ Wq,
                             const float* __restrict__ Wv, const float* __restrict__ Ws,
                             ushort_t* __restrict__ wall) {
    int g = blockIdx.x * blockDim.x + threadIdx.x;  // one per 8 elems
    if (g >= NL * 4 * DD * DD / 8) return;
    size_t flat = (size_t)g * 8;
    int l = (int)(flat / (4 * DD * DD));
    int r = (int)(flat % (4 * DD * DD));
    int m = r / (DD * DD);
    int o = r % (DD * DD);
    const float* src;
    switch (m) {
        case 0: src = Wk; break;
        case 1: src = Wq; break;
        case 2: src = Wv; break;
        default: src = Ws; break;
    }
    const float* p = src + (size_t)l * DD * DD + o;
    s16x8 ov;
#pragma unroll
    for (int j = 0; j < 8; ++j) ov[j] = (short)f2bf(p[j]);
    *(s16x8*)&wall[flat] = ov;
}

// ---------------------------------------------------------------------------
// MFMA 4-way GEMM: y[i][m][d] = sum_c in[i][c] * W_m[d][c] + b_m[d]  (bf16 out)
// Block: 256 thr = 4 waves, 64 rows x 128 cols, loops m=0..3.
// A fragments (x rows) global->reg once; W_m staged in LDS XOR-swizzled.
// ---------------------------------------------------------------------------
__global__ __launch_bounds__(256) void gemm4_mfma(
    const ushort_t* __restrict__ xb,     // [N][128] bf16
    const ushort_t* __restrict__ wall,   // [L][4][128][128] bf16
    const float* __restrict__ bk, const float* __restrict__ bq,
    const float* __restrict__ bv,
    ushort_t* __restrict__ y,            // [N][4][128] bf16
    int layer) {
    __shared__ ushort_t wlds[DD * DD];   // 32 KB

    const int t = threadIdx.x;
    const int w = t >> 6;
    const int lane = t & 63;
    const int row0 = blockIdx.x * 64;    // NN % 64 == 0

    // A fragments: rows row0+w*16+(lane&15), k = kb*32 + (lane>>4)*8 + [0..7]
    const int arow = row0 + w * 16 + (lane & 15);
    const ushort_t* ap = xb + (size_t)arow * DD + ((lane >> 4) << 3);
    s16x8 afrag[4];
#pragma unroll
    for (int kb = 0; kb < 4; ++kb) afrag[kb] = *(const s16x8*)(ap + kb * 32);

    const int dlow = lane & 15;
    const int dbase = dlow * 256;             // byte offset of row within LDS
    const int swz = (lane & 7) << 4;          // XOR swizzle term (d&7 == lane&7)
    const int g16 = (lane >> 4) << 4;         // k-group byte offset

    for (int m = 0; m < 4; ++m) {
        if (m) __syncthreads();
        // stage W_m swizzled: granule g = p*256+t; row d=g>>4, slot s=g&15
        const ushort_t* wsrc = wall + (((size_t)layer * 4 + m) << 14);
#pragma unroll
        for (int p = 0; p < 8; ++p) {
            int g = p * 256 + t;
            int d = g >> 4;
            int s = g & 15;
            int byteoff = d * 256 + ((s * 16) ^ ((d & 7) << 4));
            *(s16x8*)((char*)wlds + byteoff) = *(const s16x8*)(wsrc + (size_t)g * 8);
        }
        __syncthreads();

        f32x4 acc[8];
#pragma unroll
        for (int ct = 0; ct < 8; ++ct) acc[ct] = (f32x4){0.f, 0.f, 0.f, 0.f};

#pragma unroll
        for (int kb = 0; kb < 4; ++kb) {
#pragma unroll
            for (int ct = 0; ct < 8; ++ct) {
                s16x8 bfrag = *(const s16x8*)((char*)wlds + ct * 4096 + dbase +
                                              ((kb * 64 + g16) ^ swz));
                acc[ct] = __builtin_amdgcn_mfma_f32_16x16x32_bf16(afrag[kb], bfrag,
                                                                  acc[ct], 0, 0, 0);
            }
        }

        // epilogue: bias + bf16 store. col = ct*16+dlow, row = w*16+(lane>>4)*4+j
        const int rbase = row0 + w * 16 + ((lane >> 4) << 2);
#pragma unroll
        for (int ct = 0; ct < 8; ++ct) {
            int c0 = ct * 16 + dlow;
            float bval;
            switch (m) {
                case 0:  bval = bk[layer * DD + c0]; break;
                case 1:  bval = bq[layer * DD + c0]; break;
                case 2:  bval = bv[layer * DD + c0]; break;
                default: bval = 0.f; break;
            }
#pragma unroll
            for (int j = 0; j < 4; ++j) {
                size_t node = (size_t)(rbase + j);
                y[node * 512 + m * DD + c0] = f2bf(acc[ct][j] + bval);
            }
        }
    }
}

// ---------------------------------------------------------------------------
// Aggregation + fused epilogue (bf16 kqvs gather, fp32 math).
// One wave per node; lane owns 2 dims. Writes fp32 h (skipsum) and, if
// xb_next != null, the bf16 mirror consumed by the next layer's GEMM.
// ---------------------------------------------------------------------------
__global__ __launch_bounds__(256) void agg_kernel(
    const float* __restrict__ hin,
    const ushort_t* __restrict__ kqvs,   // [N][4][128] bf16: k,q,v,s
    const int* __restrict__ row_ptr,
    const int* __restrict__ csr_src,
    const float* __restrict__ gamma, const float* __restrict__ beta,
    float* __restrict__ hout, ushort_t* __restrict__ xb_next,
    int layer, int final_norm) {
    int wid = (blockIdx.x * blockDim.x + threadIdx.x) >> 6;
    if (wid >= NN) return;
    int lane = threadIdx.x & 63;
    int d0 = lane * 2;

    const ushort_t* base_i = kqvs + (size_t)wid * 512;
    ushort2 kraw = *(const ushort2*)&base_i[d0];
    ushort2 sraw = *(const ushort2*)&base_i[384 + d0];
    float kx = bf2f(kraw.x), ky = bf2f(kraw.y);
    float ax = bf2f(sraw.x), ay = bf2f(sraw.y);

    int s = row_ptr[wid];
    int e = row_ptr[wid + 1];
    for (int idx = s; idx < e; ++idx) {
        int j = csr_src[idx];
        const ushort_t* bj = kqvs + (size_t)j * 512;
        ushort2 qr = *(const ushort2*)&bj[128 + d0];
        ushort2 vr = *(const ushort2*)&bj[256 + d0];
        ax += sigmoidf_(kx + bf2f(qr.x)) * bf2f(vr.x);
        ay += sigmoidf_(ky + bf2f(qr.y)) * bf2f(vr.y);
    }

    float gx = gamma[layer * DD + d0], gy = gamma[layer * DD + d0 + 1];
    float btx = beta[layer * DD + d0], bty = beta[layer * DD + d0 + 1];
    float rx = fmaxf(ax * gx + btx, 0.f);
    float ry = fmaxf(ay * gy + bty, 0.f);

    float ss = rx * rx + ry * ry;
#pragma unroll
    for (int m = 1; m < 64; m <<= 1) ss += __shfl_xor(ss, m);
    float inv = 1.f / fmaxf(sqrtf(ss), 1e-12f);

    float2 xin = *(const float2*)&hin[(size_t)wid * DD + d0];
    float hx = xin.x + rx * inv;
    float hy = xin.y + ry * inv;

    if (final_norm) {
        float s2 = hx * hx + hy * hy;
#pragma unroll
        for (int m = 1; m < 64; m <<= 1) s2 += __shfl_xor(s2, m);
        float inv2 = 1.f / fmaxf(sqrtf(s2), 1e-12f);
        hx *= inv2;
        hy *= inv2;
    }
    float2 o;
    o.x = hx;
    o.y = hy;
    *(float2*)&hout[(size_t)wid * DD + d0] = o;
    if (xb_next) {
        ushort2 ob;
        ob.x = f2bf(hx);
        ob.y = f2bf(hy);
        *(ushort2*)&xb_next[(size_t)wid * DD + d0] = ob;
    }
}

// ---------------------------------------------------------------------------
extern "C" void kernel_launch(void* const* d_in, const int* in_sizes, int n_in,
                              void* d_out, int out_size, void* d_ws, size_t ws_size,
                              hipStream_t stream) {
    const float* x     = (const float*)d_in[0];
    const int*   ei    = (const int*)d_in[1];
    const float* Wk    = (const float*)d_in[2];
    const float* bk    = (const float*)d_in[3];
    const float* Wq    = (const float*)d_in[4];
    const float* bq    = (const float*)d_in[5];
    const float* Wv    = (const float*)d_in[6];
    const float* bv    = (const float*)d_in[7];
    const float* Ws    = (const float*)d_in[8];
    const float* gamma = (const float*)d_in[9];
    const float* beta  = (const float*)d_in[10];
    float* out = (float*)d_out;

    // workspace layout
    float* hb0 = (float*)d_ws;                       // [N][128] f32
    float* hb1 = hb0 + (size_t)NN * DD;              // [N][128] f32
    ushort_t* kqvs = (ushort_t*)(hb1 + (size_t)NN * DD);   // [N][4][128] bf16
    ushort_t* xb   = kqvs + (size_t)NN * 4 * DD;     // [N][128] bf16
    ushort_t* wall = xb + (size_t)NN * DD;           // [L][4][128][128] bf16
    int* srcs    = (int*)(wall + (size_t)NL * 4 * DD * DD);
    int* dsts    = srcs + NE;
    int* count   = dsts + NE;
    int* cursor  = count + NN;
    int* row_ptr = cursor + NN;
    int* csr_src = row_ptr + (NN + 1);
    int* flag    = csr_src + NE;

    // Build CSR (by dst) once; reused across all 3 layers.
    detect_kernel<<<1, 64, 0, stream>>>(ei, flag);
    convert_kernel<<<(NE + 255) / 256, 256, 0, stream>>>(ei, flag, srcs, dsts);
    zero_kernel<<<(NN + 255) / 256, 256, 0, stream>>>(count, NN);
    hist_kernel<<<(NE + 255) / 256, 256, 0, stream>>>(dsts, count);
    scan_kernel<<<1, 1024, 0, stream>>>(count, row_ptr, cursor);
    scatter_kernel<<<(NE + 255) / 256, 256, 0, stream>>>(srcs, dsts, cursor, csr_src);

    // dtype conversion
    cvt_x_kernel<<<(NN * DD / 8 + 255) / 256, 256, 0, stream>>>(x, xb);
    cvt_w_kernel<<<(NL * 4 * DD * DD / 8 + 255) / 256, 256, 0, stream>>>(Wk, Wq, Wv, Ws, wall);

    for (int l = 0; l < NL; ++l) {
        const float* hin = (l == 0) ? x : (l == 1 ? hb0 : hb1);
        float* hout = (l == 2) ? out : (l == 0 ? hb0 : hb1);
        ushort_t* xb_next = (l == 2) ? nullptr : xb;  // agg overwrites xb for next layer
        gemm4_mfma<<<NN / 64, 256, 0, stream>>>(xb, wall, bk, bq, bv, kqvs, l);
        agg_kernel<<<(NN * 64) / 256, 256, 0, stream>>>(hin, kqvs, row_ptr, csr_src, gamma,
                                                        beta, hout, xb_next, l,
                                                        (l == NL - 1) ? 1 : 0);
    }
}

// Round 3
// 383.335 us; speedup vs baseline: 2.0442x; 1.2327x over previous
//
#include <hip/hip_runtime.h>
#include <math.h>

#define NN 40000
#define NE 640000
#define DD 128
#define NL 3
#define SCAN_NBLK ((NN + 255) / 256)   // 157

typedef short s16x8 __attribute__((ext_vector_type(8)));
typedef float f32x4 __attribute__((ext_vector_type(4)));
typedef unsigned short ushort_t;

__device__ __forceinline__ float sigmoidf_(float x) {
    return 1.0f / (1.0f + __expf(-x));
}

// bf16 <-> f32 via bit ops (RNE)
__device__ __forceinline__ ushort_t f2bf(float f) {
    unsigned int u = __float_as_uint(f);
    u = (u + 0x7FFFu + ((u >> 16) & 1u)) >> 16;
    return (ushort_t)u;
}
__device__ __forceinline__ float bf2f(ushort_t h) {
    return __uint_as_float(((unsigned int)h) << 16);
}

// ---------------------------------------------------------------------------
// Edge preprocessing
// ---------------------------------------------------------------------------
__global__ void detect_kernel(const int* __restrict__ ei, int* __restrict__ flag) {
    if (threadIdx.x == 0) {
        int is64 = 1;
        for (int e = 0; e < 32; ++e) {
            if (ei[2 * e + 1] != 0) { is64 = 0; break; }
        }
        *flag = is64;
    }
}

__global__ void zero_kernel(int* __restrict__ p, int n) {
    int i = blockIdx.x * blockDim.x + threadIdx.x;
    if (i < n) p[i] = 0;
}

// convert int64/int32 edge_index -> int32 srcs/dsts, and histogram dst degree
__global__ void convert_hist_kernel(const int* __restrict__ ei, const int* __restrict__ flag,
                                    int* __restrict__ srcs, int* __restrict__ dsts,
                                    int* __restrict__ count) {
    int e = blockIdx.x * blockDim.x + threadIdx.x;
    if (e >= NE) return;
    int s, d;
    if (*flag) {
        s = ei[2 * e];
        d = ei[2 * (NE + e)];
    } else {
        s = ei[e];
        d = ei[NE + e];
    }
    srcs[e] = s;
    dsts[e] = d;
    atomicAdd(&count[d], 1);
}

// Distributed scan, phase 1: per-256-block local exclusive scan + block total.
__global__ __launch_bounds__(256) void scan1_kernel(const int* __restrict__ count,
                                                    int* __restrict__ row_ptr,
                                                    int* __restrict__ blocksum) {
    __shared__ int tmp[256];
    int t = threadIdx.x;
    int i = blockIdx.x * 256 + t;
    int v = (i < NN) ? count[i] : 0;
    tmp[t] = v;
    __syncthreads();
    for (int off = 1; off < 256; off <<= 1) {
        int u = (t >= off) ? tmp[t - off] : 0;
        __syncthreads();
        tmp[t] += u;
        __syncthreads();
    }
    if (i < NN) row_ptr[i] = tmp[t] - v;  // exclusive within block
    if (t == 255) blocksum[blockIdx.x] = tmp[255];
}

// phase 2: scan the 157 block sums (single small block).
__global__ __launch_bounds__(256) void scan2_kernel(const int* __restrict__ blocksum,
                                                    int* __restrict__ blockoff) {
    __shared__ int tmp[256];
    int t = threadIdx.x;
    int v = (t < SCAN_NBLK) ? blocksum[t] : 0;
    tmp[t] = v;
    __syncthreads();
    for (int off = 1; off < 256; off <<= 1) {
        int u = (t >= off) ? tmp[t - off] : 0;
        __syncthreads();
        tmp[t] += u;
        __syncthreads();
    }
    if (t < SCAN_NBLK) blockoff[t] = tmp[t] - v;
}

// phase 3: add block offsets; materialize row_ptr and cursor.
__global__ void scan3_kernel(int* __restrict__ row_ptr, const int* __restrict__ blockoff,
                             int* __restrict__ cursor) {
    int i = blockIdx.x * blockDim.x + threadIdx.x;
    if (i >= NN) return;
    int r = row_ptr[i] + blockoff[i >> 8];
    row_ptr[i] = r;
    cursor[i] = r;
    if (i == 0) row_ptr[NN] = NE;
}

__global__ void scatter_kernel(const int* __restrict__ srcs, const int* __restrict__ dsts,
                               int* __restrict__ cursor, int* __restrict__ csr_src) {
    int e = blockIdx.x * blockDim.x + threadIdx.x;
    if (e >= NE) return;
    int i = dsts[e];
    int pos = atomicAdd(&cursor[i], 1);
    csr_src[pos] = srcs[e];
}

// ---------------------------------------------------------------------------
// dtype conversion: x -> bf16, weights -> bf16 packed [L][4][128][128]
// ---------------------------------------------------------------------------
__global__ void cvt_x_kernel(const float* __restrict__ x, ushort_t* __restrict__ xb) {
    int i = blockIdx.x * blockDim.x + threadIdx.x;
    if (i >= NN * DD / 8) return;
    const float* p = x + (size_t)i * 8;
    s16x8 o;
#pragma unroll
    for (int j = 0; j < 8; ++j) o[j] = (short)f2bf(p[j]);
    *(s16x8*)&xb[(size_t)i * 8] = o;
}

__global__ void cvt_w_kernel(const float* __restrict__ Wk, const float* __restrict__ Wq,
                             const float* __restrict__ Wv, const float* __restrict__ Ws,
                             ushort_t* __restrict__ wall) {
    int g = blockIdx.x * blockDim.x + threadIdx.x;
    if (g >= NL * 4 * DD * DD / 8) return;
    size_t flat = (size_t)g * 8;
    int l = (int)(flat / (4 * DD * DD));
    int r = (int)(flat % (4 * DD * DD));
    int m = r / (DD * DD);
    int o = r % (DD * DD);
    const float* src;
    switch (m) {
        case 0: src = Wk; break;
        case 1: src = Wq; break;
        case 2: src = Wv; break;
        default: src = Ws; break;
    }
    const float* p = src + (size_t)l * DD * DD + o;
    s16x8 ov;
#pragma unroll
    for (int j = 0; j < 8; ++j) ov[j] = (short)f2bf(p[j]);
    *(s16x8*)&wall[flat] = ov;
}

// ---------------------------------------------------------------------------
// MFMA 4-way GEMM. Output layout per node (ushort offsets within 512):
//   [0..127]   k
//   [128..383] q,v interleaved: q_d at 128+2d, v_d at 129+2d
//   [384..511] s (skip)
// m=1 (q) results are held in registers and combined into packed 4B stores
// during the m=2 (v) pass, keeping stores coalesced.
// ---------------------------------------------------------------------------
__global__ __launch_bounds__(256) void gemm4_mfma(
    const ushort_t* __restrict__ xb,     // [N][128] bf16
    const ushort_t* __restrict__ wall,   // [L][4][128][128] bf16
    const float* __restrict__ bk, const float* __restrict__ bq,
    const float* __restrict__ bv,
    ushort_t* __restrict__ y,            // [N][512] bf16
    int layer) {
    __shared__ ushort_t wlds[DD * DD];   // 32 KB

    const int t = threadIdx.x;
    const int w = t >> 6;
    const int lane = t & 63;
    const int row0 = blockIdx.x * 64;    // NN % 64 == 0

    const int arow = row0 + w * 16 + (lane & 15);
    const ushort_t* ap = xb + (size_t)arow * DD + ((lane >> 4) << 3);
    s16x8 afrag[4];
#pragma unroll
    for (int kb = 0; kb < 4; ++kb) afrag[kb] = *(const s16x8*)(ap + kb * 32);

    const int dlow = lane & 15;
    const int dbase = dlow * 256;
    const int swz = (lane & 7) << 4;
    const int g16 = (lane >> 4) << 4;

    unsigned int qs[8][2];  // saved bf16 q results (packed pairs), m==1 -> m==2

    for (int m = 0; m < 4; ++m) {
        if (m) __syncthreads();
        const ushort_t* wsrc = wall + (((size_t)layer * 4 + m) << 14);
#pragma unroll
        for (int p = 0; p < 8; ++p) {
            int g = p * 256 + t;
            int d = g >> 4;
            int s = g & 15;
            int byteoff = d * 256 + ((s * 16) ^ ((d & 7) << 4));
            *(s16x8*)((char*)wlds + byteoff) = *(const s16x8*)(wsrc + (size_t)g * 8);
        }
        __syncthreads();

        f32x4 acc[8];
#pragma unroll
        for (int ct = 0; ct < 8; ++ct) acc[ct] = (f32x4){0.f, 0.f, 0.f, 0.f};

#pragma unroll
        for (int kb = 0; kb < 4; ++kb) {
#pragma unroll
            for (int ct = 0; ct < 8; ++ct) {
                s16x8 bfrag = *(const s16x8*)((char*)wlds + ct * 4096 + dbase +
                                              ((kb * 64 + g16) ^ swz));
                acc[ct] = __builtin_amdgcn_mfma_f32_16x16x32_bf16(afrag[kb], bfrag,
                                                                  acc[ct], 0, 0, 0);
            }
        }

        const int rbase = row0 + w * 16 + ((lane >> 4) << 2);
#pragma unroll
        for (int ct = 0; ct < 8; ++ct) {
            int c0 = ct * 16 + dlow;
            if (m == 0) {
                float bval = bk[layer * DD + c0];
#pragma unroll
                for (int j = 0; j < 4; ++j)
                    y[(size_t)(rbase + j) * 512 + c0] = f2bf(acc[ct][j] + bval);
            } else if (m == 1) {
                float bval = bq[layer * DD + c0];
                qs[ct][0] = (unsigned int)f2bf(acc[ct][0] + bval) |
                            ((unsigned int)f2bf(acc[ct][1] + bval) << 16);
                qs[ct][1] = (unsigned int)f2bf(acc[ct][2] + bval) |
                            ((unsigned int)f2bf(acc[ct][3] + bval) << 16);
            } else if (m == 2) {
                float bval = bv[layer * DD + c0];
#pragma unroll
                for (int j = 0; j < 4; ++j) {
                    unsigned int q16 = (qs[ct][j >> 1] >> ((j & 1) * 16)) & 0xFFFFu;
                    unsigned int val = q16 | ((unsigned int)f2bf(acc[ct][j] + bval) << 16);
                    *(unsigned int*)&y[(size_t)(rbase + j) * 512 + 128 + 2 * c0] = val;
                }
            } else {
#pragma unroll
                for (int j = 0; j < 4; ++j)
                    y[(size_t)(rbase + j) * 512 + 384 + c0] = f2bf(acc[ct][j]);
            }
        }
    }
}

// ---------------------------------------------------------------------------
// Aggregation + fused epilogue. One wave per node; lane owns dims 2l, 2l+1.
// Per edge: one 8B load (q,v interleaved) per lane = 512B contiguous/edge.
// ---------------------------------------------------------------------------
__global__ __launch_bounds__(256) void agg_kernel(
    const float* __restrict__ hin,
    const ushort_t* __restrict__ kqvs,   // [N][512] bf16 (k | qv | s)
    const int* __restrict__ row_ptr,
    const int* __restrict__ csr_src,
    const float* __restrict__ gamma, const float* __restrict__ beta,
    float* __restrict__ hout, ushort_t* __restrict__ xb_next,
    int layer, int final_norm) {
    int wid = (blockIdx.x * blockDim.x + threadIdx.x) >> 6;
    if (wid >= NN) return;
    int lane = threadIdx.x & 63;
    int d0 = lane * 2;

    const ushort_t* base_i = kqvs + (size_t)wid * 512;
    ushort2 kraw = *(const ushort2*)&base_i[d0];
    ushort2 sraw = *(const ushort2*)&base_i[384 + d0];
    float kx = bf2f(kraw.x), ky = bf2f(kraw.y);
    float ax = bf2f(sraw.x), ay = bf2f(sraw.y);

    int s = row_ptr[wid];
    int e = row_ptr[wid + 1];
    for (int idx = s; idx < e; ++idx) {
        int j = csr_src[idx];
        const ushort_t* bj = kqvs + (size_t)j * 512;
        ushort4 qv = *(const ushort4*)&bj[128 + 4 * lane];
        ax += sigmoidf_(kx + bf2f(qv.x)) * bf2f(qv.y);
        ay += sigmoidf_(ky + bf2f(qv.z)) * bf2f(qv.w);
    }

    float gx = gamma[layer * DD + d0], gy = gamma[layer * DD + d0 + 1];
    float btx = beta[layer * DD + d0], bty = beta[layer * DD + d0 + 1];
    float rx = fmaxf(ax * gx + btx, 0.f);
    float ry = fmaxf(ay * gy + bty, 0.f);

    float ss = rx * rx + ry * ry;
#pragma unroll
    for (int m = 1; m < 64; m <<= 1) ss += __shfl_xor(ss, m);
    float inv = 1.f / fmaxf(sqrtf(ss), 1e-12f);

    float2 xin = *(const float2*)&hin[(size_t)wid * DD + d0];
    float hx = xin.x + rx * inv;
    float hy = xin.y + ry * inv;

    if (final_norm) {
        float s2 = hx * hx + hy * hy;
#pragma unroll
        for (int m = 1; m < 64; m <<= 1) s2 += __shfl_xor(s2, m);
        float inv2 = 1.f / fmaxf(sqrtf(s2), 1e-12f);
        hx *= inv2;
        hy *= inv2;
    }
    float2 o;
    o.x = hx;
    o.y = hy;
    *(float2*)&hout[(size_t)wid * DD + d0] = o;
    if (xb_next) {
        ushort2 ob;
        ob.x = f2bf(hx);
        ob.y = f2bf(hy);
        *(ushort2*)&xb_next[(size_t)wid * DD + d0] = ob;
    }
}

// ---------------------------------------------------------------------------
extern "C" void kernel_launch(void* const* d_in, const int* in_sizes, int n_in,
                              void* d_out, int out_size, void* d_ws, size_t ws_size,
                              hipStream_t stream) {
    const float* x     = (const float*)d_in[0];
    const int*   ei    = (const int*)d_in[1];
    const float* Wk    = (const float*)d_in[2];
    const float* bk    = (const float*)d_in[3];
    const float* Wq    = (const float*)d_in[4];
    const float* bq    = (const float*)d_in[5];
    const float* Wv    = (const float*)d_in[6];
    const float* bv    = (const float*)d_in[7];
    const float* Ws    = (const float*)d_in[8];
    const float* gamma = (const float*)d_in[9];
    const float* beta  = (const float*)d_in[10];
    float* out = (float*)d_out;

    // workspace layout
    float* hb0 = (float*)d_ws;                           // [N][128] f32
    float* hb1 = hb0 + (size_t)NN * DD;                  // [N][128] f32
    ushort_t* kqvs = (ushort_t*)(hb1 + (size_t)NN * DD); // [N][512] bf16
    ushort_t* xb   = kqvs + (size_t)NN * 4 * DD;         // [N][128] bf16
    ushort_t* wall = xb + (size_t)NN * DD;               // [L][4][128][128] bf16
    int* srcs     = (int*)(wall + (size_t)NL * 4 * DD * DD);
    int* dsts     = srcs + NE;
    int* count    = dsts + NE;
    int* cursor   = count + NN;
    int* row_ptr  = cursor + NN;
    int* csr_src  = row_ptr + (NN + 1);
    int* flag     = csr_src + NE;
    int* blocksum = flag + 4;
    int* blockoff = blocksum + SCAN_NBLK;

    // Build CSR (by dst); reused across all 3 layers.
    detect_kernel<<<1, 64, 0, stream>>>(ei, flag);
    zero_kernel<<<(NN + 255) / 256, 256, 0, stream>>>(count, NN);
    convert_hist_kernel<<<(NE + 255) / 256, 256, 0, stream>>>(ei, flag, srcs, dsts, count);
    scan1_kernel<<<SCAN_NBLK, 256, 0, stream>>>(count, row_ptr, blocksum);
    scan2_kernel<<<1, 256, 0, stream>>>(blocksum, blockoff);
    scan3_kernel<<<(NN + 255) / 256, 256, 0, stream>>>(row_ptr, blockoff, cursor);
    scatter_kernel<<<(NE + 255) / 256, 256, 0, stream>>>(srcs, dsts, cursor, csr_src);

    // dtype conversion
    cvt_x_kernel<<<(NN * DD / 8 + 255) / 256, 256, 0, stream>>>(x, xb);
    cvt_w_kernel<<<(NL * 4 * DD * DD / 8 + 255) / 256, 256, 0, stream>>>(Wk, Wq, Wv, Ws, wall);

    for (int l = 0; l < NL; ++l) {
        const float* hin = (l == 0) ? x : (l == 1 ? hb0 : hb1);
        float* hout = (l == 2) ? out : (l == 0 ? hb0 : hb1);
        ushort_t* xb_next = (l == 2) ? nullptr : xb;
        gemm4_mfma<<<NN / 64, 256, 0, stream>>>(xb, wall, bk, bq, bv, kqvs, l);
        agg_kernel<<<(NN * 64) / 256, 256, 0, stream>>>(hin, kqvs, row_ptr, csr_src, gamma,
                                                        beta, hout, xb_next, l,
                                                        (l == NL - 1) ? 1 : 0);
    }
}

// Round 4
// 284.817 us; speedup vs baseline: 2.7512x; 1.3459x over previous
//
#include <hip/hip_runtime.h>
#include <math.h>

#define NN 40000
#define NE 640000
#define DD 128
#define NL 3
#define SCAN_NBLK ((NN + 255) / 256)   // 157

typedef short s16x8 __attribute__((ext_vector_type(8)));
typedef float f32x4 __attribute__((ext_vector_type(4)));
typedef unsigned short ushort_t;

// bf16 <-> f32 via bit ops (RNE)
__device__ __forceinline__ ushort_t f2bf(float f) {
    unsigned int u = __float_as_uint(f);
    u = (u + 0x7FFFu + ((u >> 16) & 1u)) >> 16;
    return (ushort_t)u;
}
__device__ __forceinline__ float bf2f(ushort_t h) {
    return __uint_as_float(((unsigned int)h) << 16);
}

// fast sigmoid: v_exp + v_rcp (1 ulp rcp; error << bf16 noise floor)
__device__ __forceinline__ float fsig(float x) {
    return __builtin_amdgcn_rcpf(1.0f + __expf(-x));
}

// ---------------------------------------------------------------------------
// Edge preprocessing
// ---------------------------------------------------------------------------
__global__ void detect_kernel(const int* __restrict__ ei, int* __restrict__ flag) {
    if (threadIdx.x == 0) {
        int is64 = 1;
        for (int e = 0; e < 32; ++e) {
            if (ei[2 * e + 1] != 0) { is64 = 0; break; }
        }
        *flag = is64;
    }
}

__global__ void zero_kernel(int* __restrict__ p, int n) {
    int i = blockIdx.x * blockDim.x + threadIdx.x;
    if (i < n) p[i] = 0;
}

__global__ void convert_hist_kernel(const int* __restrict__ ei, const int* __restrict__ flag,
                                    int* __restrict__ srcs, int* __restrict__ dsts,
                                    int* __restrict__ count) {
    int e = blockIdx.x * blockDim.x + threadIdx.x;
    if (e >= NE) return;
    int s, d;
    if (*flag) {
        s = ei[2 * e];
        d = ei[2 * (NE + e)];
    } else {
        s = ei[e];
        d = ei[NE + e];
    }
    srcs[e] = s;
    dsts[e] = d;
    atomicAdd(&count[d], 1);
}

__global__ __launch_bounds__(256) void scan1_kernel(const int* __restrict__ count,
                                                    int* __restrict__ row_ptr,
                                                    int* __restrict__ blocksum) {
    __shared__ int tmp[256];
    int t = threadIdx.x;
    int i = blockIdx.x * 256 + t;
    int v = (i < NN) ? count[i] : 0;
    tmp[t] = v;
    __syncthreads();
    for (int off = 1; off < 256; off <<= 1) {
        int u = (t >= off) ? tmp[t - off] : 0;
        __syncthreads();
        tmp[t] += u;
        __syncthreads();
    }
    if (i < NN) row_ptr[i] = tmp[t] - v;
    if (t == 255) blocksum[blockIdx.x] = tmp[255];
}

__global__ __launch_bounds__(256) void scan2_kernel(const int* __restrict__ blocksum,
                                                    int* __restrict__ blockoff) {
    __shared__ int tmp[256];
    int t = threadIdx.x;
    int v = (t < SCAN_NBLK) ? blocksum[t] : 0;
    tmp[t] = v;
    __syncthreads();
    for (int off = 1; off < 256; off <<= 1) {
        int u = (t >= off) ? tmp[t - off] : 0;
        __syncthreads();
        tmp[t] += u;
        __syncthreads();
    }
    if (t < SCAN_NBLK) blockoff[t] = tmp[t] - v;
}

__global__ void scan3_kernel(int* __restrict__ row_ptr, const int* __restrict__ blockoff,
                             int* __restrict__ cursor) {
    int i = blockIdx.x * blockDim.x + threadIdx.x;
    if (i >= NN) return;
    int r = row_ptr[i] + blockoff[i >> 8];
    row_ptr[i] = r;
    cursor[i] = r;
    if (i == 0) row_ptr[NN] = NE;
}

__global__ void scatter_kernel(const int* __restrict__ srcs, const int* __restrict__ dsts,
                               int* __restrict__ cursor, int* __restrict__ csr_src) {
    int e = blockIdx.x * blockDim.x + threadIdx.x;
    if (e >= NE) return;
    int i = dsts[e];
    int pos = atomicAdd(&cursor[i], 1);
    csr_src[pos] = srcs[e];
}

// ---------------------------------------------------------------------------
// dtype conversion
// ---------------------------------------------------------------------------
__global__ void cvt_x_kernel(const float* __restrict__ x, ushort_t* __restrict__ xb) {
    int i = blockIdx.x * blockDim.x + threadIdx.x;
    if (i >= NN * DD / 8) return;
    const float* p = x + (size_t)i * 8;
    s16x8 o;
#pragma unroll
    for (int j = 0; j < 8; ++j) o[j] = (short)f2bf(p[j]);
    *(s16x8*)&xb[(size_t)i * 8] = o;
}

__global__ void cvt_w_kernel(const float* __restrict__ Wk, const float* __restrict__ Wq,
                             const float* __restrict__ Wv, const float* __restrict__ Ws,
                             ushort_t* __restrict__ wall) {
    int g = blockIdx.x * blockDim.x + threadIdx.x;
    if (g >= NL * 4 * DD * DD / 8) return;
    size_t flat = (size_t)g * 8;
    int l = (int)(flat / (4 * DD * DD));
    int r = (int)(flat % (4 * DD * DD));
    int m = r / (DD * DD);
    int o = r % (DD * DD);
    const float* src;
    switch (m) {
        case 0: src = Wk; break;
        case 1: src = Wq; break;
        case 2: src = Wv; break;
        default: src = Ws; break;
    }
    const float* p = src + (size_t)l * DD * DD + o;
    s16x8 ov;
#pragma unroll
    for (int j = 0; j < 8; ++j) ov[j] = (short)f2bf(p[j]);
    *(s16x8*)&wall[flat] = ov;
}

// ---------------------------------------------------------------------------
// MFMA 4-way GEMM. Output layout per node (ushort offsets within 512):
//   [0..127] k | [128..383] q,v interleaved (q_d at 128+2d, v_d at 129+2d)
//   [384..511] s
// ---------------------------------------------------------------------------
__global__ __launch_bounds__(256) void gemm4_mfma(
    const ushort_t* __restrict__ xb,
    const ushort_t* __restrict__ wall,
    const float* __restrict__ bk, const float* __restrict__ bq,
    const float* __restrict__ bv,
    ushort_t* __restrict__ y,
    int layer) {
    __shared__ ushort_t wlds[DD * DD];

    const int t = threadIdx.x;
    const int w = t >> 6;
    const int lane = t & 63;
    const int row0 = blockIdx.x * 64;

    const int arow = row0 + w * 16 + (lane & 15);
    const ushort_t* ap = xb + (size_t)arow * DD + ((lane >> 4) << 3);
    s16x8 afrag[4];
#pragma unroll
    for (int kb = 0; kb < 4; ++kb) afrag[kb] = *(const s16x8*)(ap + kb * 32);

    const int dlow = lane & 15;
    const int dbase = dlow * 256;
    const int swz = (lane & 7) << 4;
    const int g16 = (lane >> 4) << 4;

    unsigned int qs[8][2];

    for (int m = 0; m < 4; ++m) {
        if (m) __syncthreads();
        const ushort_t* wsrc = wall + (((size_t)layer * 4 + m) << 14);
#pragma unroll
        for (int p = 0; p < 8; ++p) {
            int g = p * 256 + t;
            int d = g >> 4;
            int s = g & 15;
            int byteoff = d * 256 + ((s * 16) ^ ((d & 7) << 4));
            *(s16x8*)((char*)wlds + byteoff) = *(const s16x8*)(wsrc + (size_t)g * 8);
        }
        __syncthreads();

        f32x4 acc[8];
#pragma unroll
        for (int ct = 0; ct < 8; ++ct) acc[ct] = (f32x4){0.f, 0.f, 0.f, 0.f};

#pragma unroll
        for (int kb = 0; kb < 4; ++kb) {
#pragma unroll
            for (int ct = 0; ct < 8; ++ct) {
                s16x8 bfrag = *(const s16x8*)((char*)wlds + ct * 4096 + dbase +
                                              ((kb * 64 + g16) ^ swz));
                acc[ct] = __builtin_amdgcn_mfma_f32_16x16x32_bf16(afrag[kb], bfrag,
                                                                  acc[ct], 0, 0, 0);
            }
        }

        const int rbase = row0 + w * 16 + ((lane >> 4) << 2);
#pragma unroll
        for (int ct = 0; ct < 8; ++ct) {
            int c0 = ct * 16 + dlow;
            if (m == 0) {
                float bval = bk[layer * DD + c0];
#pragma unroll
                for (int j = 0; j < 4; ++j)
                    y[(size_t)(rbase + j) * 512 + c0] = f2bf(acc[ct][j] + bval);
            } else if (m == 1) {
                float bval = bq[layer * DD + c0];
                qs[ct][0] = (unsigned int)f2bf(acc[ct][0] + bval) |
                            ((unsigned int)f2bf(acc[ct][1] + bval) << 16);
                qs[ct][1] = (unsigned int)f2bf(acc[ct][2] + bval) |
                            ((unsigned int)f2bf(acc[ct][3] + bval) << 16);
            } else if (m == 2) {
                float bval = bv[layer * DD + c0];
#pragma unroll
                for (int j = 0; j < 4; ++j) {
                    unsigned int q16 = (qs[ct][j >> 1] >> ((j & 1) * 16)) & 0xFFFFu;
                    unsigned int val = q16 | ((unsigned int)f2bf(acc[ct][j] + bval) << 16);
                    *(unsigned int*)&y[(size_t)(rbase + j) * 512 + 128 + 2 * c0] = val;
                }
            } else {
#pragma unroll
                for (int j = 0; j < 4; ++j)
                    y[(size_t)(rbase + j) * 512 + 384 + c0] = f2bf(acc[ct][j]);
            }
        }
    }
}

// ---------------------------------------------------------------------------
// Aggregation + fused epilogue. One wave per node; lane owns dims 2l,2l+1.
// Edge loop unrolled x4: 4 uniform index loads then 4 independent 8B gathers
// in flight. Sigmoid uses v_exp + v_rcp (no precise-div sequence).
// ---------------------------------------------------------------------------
__global__ __launch_bounds__(256) void agg_kernel(
    const float* __restrict__ hin,
    const ushort_t* __restrict__ kqvs,   // [N][512] bf16 (k | qv | s)
    const int* __restrict__ row_ptr,
    const int* __restrict__ csr_src,
    const float* __restrict__ gamma, const float* __restrict__ beta,
    float* __restrict__ hout, ushort_t* __restrict__ xb_next,
    int layer, int final_norm) {
    int wid = (blockIdx.x * blockDim.x + threadIdx.x) >> 6;
    if (wid >= NN) return;
    int lane = threadIdx.x & 63;
    int d0 = lane * 2;

    const ushort_t* base_i = kqvs + ((unsigned)wid << 9);
    ushort2 kraw = *(const ushort2*)&base_i[d0];
    ushort2 sraw = *(const ushort2*)&base_i[384 + d0];
    float kx = bf2f(kraw.x), ky = bf2f(kraw.y);
    float ax = bf2f(sraw.x), ay = bf2f(sraw.y);

    const unsigned qvoff = 128u + 4u * (unsigned)lane;  // ushort offset in record
    int s = row_ptr[wid];
    int e = row_ptr[wid + 1];
    int idx = s;

    for (; idx + 4 <= e; idx += 4) {
        int j0 = csr_src[idx];
        int j1 = csr_src[idx + 1];
        int j2 = csr_src[idx + 2];
        int j3 = csr_src[idx + 3];
        ushort4 a0 = *(const ushort4*)&kqvs[((unsigned)j0 << 9) + qvoff];
        ushort4 a1 = *(const ushort4*)&kqvs[((unsigned)j1 << 9) + qvoff];
        ushort4 a2 = *(const ushort4*)&kqvs[((unsigned)j2 << 9) + qvoff];
        ushort4 a3 = *(const ushort4*)&kqvs[((unsigned)j3 << 9) + qvoff];
        ax += fsig(kx + bf2f(a0.x)) * bf2f(a0.y);
        ay += fsig(ky + bf2f(a0.z)) * bf2f(a0.w);
        ax += fsig(kx + bf2f(a1.x)) * bf2f(a1.y);
        ay += fsig(ky + bf2f(a1.z)) * bf2f(a1.w);
        ax += fsig(kx + bf2f(a2.x)) * bf2f(a2.y);
        ay += fsig(ky + bf2f(a2.z)) * bf2f(a2.w);
        ax += fsig(kx + bf2f(a3.x)) * bf2f(a3.y);
        ay += fsig(ky + bf2f(a3.z)) * bf2f(a3.w);
    }
    for (; idx < e; ++idx) {
        int j = csr_src[idx];
        ushort4 a = *(const ushort4*)&kqvs[((unsigned)j << 9) + qvoff];
        ax += fsig(kx + bf2f(a.x)) * bf2f(a.y);
        ay += fsig(ky + bf2f(a.z)) * bf2f(a.w);
    }

    float gx = gamma[layer * DD + d0], gy = gamma[layer * DD + d0 + 1];
    float btx = beta[layer * DD + d0], bty = beta[layer * DD + d0 + 1];
    float rx = fmaxf(ax * gx + btx, 0.f);
    float ry = fmaxf(ay * gy + bty, 0.f);

    float ss = rx * rx + ry * ry;
#pragma unroll
    for (int m = 1; m < 64; m <<= 1) ss += __shfl_xor(ss, m);
    float inv = __builtin_amdgcn_rcpf(fmaxf(sqrtf(ss), 1e-12f));

    float2 xin = *(const float2*)&hin[(size_t)wid * DD + d0];
    float hx = xin.x + rx * inv;
    float hy = xin.y + ry * inv;

    if (final_norm) {
        float s2 = hx * hx + hy * hy;
#pragma unroll
        for (int m = 1; m < 64; m <<= 1) s2 += __shfl_xor(s2, m);
        float inv2 = __builtin_amdgcn_rcpf(fmaxf(sqrtf(s2), 1e-12f));
        hx *= inv2;
        hy *= inv2;
    }
    float2 o;
    o.x = hx;
    o.y = hy;
    *(float2*)&hout[(size_t)wid * DD + d0] = o;
    if (xb_next) {
        ushort2 ob;
        ob.x = f2bf(hx);
        ob.y = f2bf(hy);
        *(ushort2*)&xb_next[(size_t)wid * DD + d0] = ob;
    }
}

// ---------------------------------------------------------------------------
extern "C" void kernel_launch(void* const* d_in, const int* in_sizes, int n_in,
                              void* d_out, int out_size, void* d_ws, size_t ws_size,
                              hipStream_t stream) {
    const float* x     = (const float*)d_in[0];
    const int*   ei    = (const int*)d_in[1];
    const float* Wk    = (const float*)d_in[2];
    const float* bk    = (const float*)d_in[3];
    const float* Wq    = (const float*)d_in[4];
    const float* bq    = (const float*)d_in[5];
    const float* Wv    = (const float*)d_in[6];
    const float* bv    = (const float*)d_in[7];
    const float* Ws    = (const float*)d_in[8];
    const float* gamma = (const float*)d_in[9];
    const float* beta  = (const float*)d_in[10];
    float* out = (float*)d_out;

    float* hb0 = (float*)d_ws;
    float* hb1 = hb0 + (size_t)NN * DD;
    ushort_t* kqvs = (ushort_t*)(hb1 + (size_t)NN * DD);
    ushort_t* xb   = kqvs + (size_t)NN * 4 * DD;
    ushort_t* wall = xb + (size_t)NN * DD;
    int* srcs     = (int*)(wall + (size_t)NL * 4 * DD * DD);
    int* dsts     = srcs + NE;
    int* count    = dsts + NE;
    int* cursor   = count + NN;
    int* row_ptr  = cursor + NN;
    int* csr_src  = row_ptr + (NN + 1);
    int* flag     = csr_src + NE;
    int* blocksum = flag + 4;
    int* blockoff = blocksum + SCAN_NBLK;

    detect_kernel<<<1, 64, 0, stream>>>(ei, flag);
    zero_kernel<<<(NN + 255) / 256, 256, 0, stream>>>(count, NN);
    convert_hist_kernel<<<(NE + 255) / 256, 256, 0, stream>>>(ei, flag, srcs, dsts, count);
    scan1_kernel<<<SCAN_NBLK, 256, 0, stream>>>(count, row_ptr, blocksum);
    scan2_kernel<<<1, 256, 0, stream>>>(blocksum, blockoff);
    scan3_kernel<<<(NN + 255) / 256, 256, 0, stream>>>(row_ptr, blockoff, cursor);
    scatter_kernel<<<(NE + 255) / 256, 256, 0, stream>>>(srcs, dsts, cursor, csr_src);

    cvt_x_kernel<<<(NN * DD / 8 + 255) / 256, 256, 0, stream>>>(x, xb);
    cvt_w_kernel<<<(NL * 4 * DD * DD / 8 + 255) / 256, 256, 0, stream>>>(Wk, Wq, Wv, Ws, wall);

    for (int l = 0; l < NL; ++l) {
        const float* hin = (l == 0) ? x : (l == 1 ? hb0 : hb1);
        float* hout = (l == 2) ? out : (l == 0 ? hb0 : hb1);
        ushort_t* xb_next = (l == 2) ? nullptr : xb;
        gemm4_mfma<<<NN / 64, 256, 0, stream>>>(xb, wall, bk, bq, bv, kqvs, l);
        agg_kernel<<<(NN * 64) / 256, 256, 0, stream>>>(hin, kqvs, row_ptr, csr_src, gamma,
                                                        beta, hout, xb_next, l,
                                                        (l == NL - 1) ? 1 : 0);
    }
}

// Round 5
// 278.065 us; speedup vs baseline: 2.8181x; 1.0243x over previous
//
#include <hip/hip_runtime.h>
#include <math.h>

#define NN 40000
#define NE 640000
#define DD 128
#define NL 3
#define SCAN_NBLK ((NN + 255) / 256)   // 157
#define NEG_LOG2E -1.4426950408889634f

typedef short s16x8 __attribute__((ext_vector_type(8)));
typedef float f32x4 __attribute__((ext_vector_type(4)));
typedef unsigned short ushort_t;

// bf16 <-> f32 via bit ops (RNE)
__device__ __forceinline__ ushort_t f2bf(float f) {
    unsigned int u = __float_as_uint(f);
    u = (u + 0x7FFFu + ((u >> 16) & 1u)) >> 16;
    return (ushort_t)u;
}
__device__ __forceinline__ float bf2f(ushort_t h) {
    return __uint_as_float(((unsigned int)h) << 16);
}

// ---------------------------------------------------------------------------
// Edge preprocessing
// ---------------------------------------------------------------------------
__global__ void convert_hist_kernel(const int* __restrict__ ei,
                                    int* __restrict__ srcs, int* __restrict__ dsts,
                                    int* __restrict__ count) {
    __shared__ int sh_is64;
    if (threadIdx.x == 0) {
        // int64 edge_index => high words of first 32 values all zero (idx<40000).
        int is64 = 1;
        for (int k = 0; k < 32; ++k)
            if (ei[2 * k + 1] != 0) { is64 = 0; break; }
        sh_is64 = is64;
    }
    __syncthreads();
    int e = blockIdx.x * blockDim.x + threadIdx.x;
    if (e >= NE) return;
    int s, d;
    if (sh_is64) {
        s = ei[2 * e];
        d = ei[2 * (NE + e)];
    } else {
        s = ei[e];
        d = ei[NE + e];
    }
    srcs[e] = s;
    dsts[e] = d;
    atomicAdd(&count[d], 1);
}

__global__ __launch_bounds__(256) void scan1_kernel(const int* __restrict__ count,
                                                    int* __restrict__ row_ptr,
                                                    int* __restrict__ blocksum) {
    __shared__ int tmp[256];
    int t = threadIdx.x;
    int i = blockIdx.x * 256 + t;
    int v = (i < NN) ? count[i] : 0;
    tmp[t] = v;
    __syncthreads();
    for (int off = 1; off < 256; off <<= 1) {
        int u = (t >= off) ? tmp[t - off] : 0;
        __syncthreads();
        tmp[t] += u;
        __syncthreads();
    }
    if (i < NN) row_ptr[i] = tmp[t] - v;
    if (t == 255) blocksum[blockIdx.x] = tmp[255];
}

__global__ __launch_bounds__(256) void scan2_kernel(const int* __restrict__ blocksum,
                                                    int* __restrict__ blockoff) {
    __shared__ int tmp[256];
    int t = threadIdx.x;
    int v = (t < SCAN_NBLK) ? blocksum[t] : 0;
    tmp[t] = v;
    __syncthreads();
    for (int off = 1; off < 256; off <<= 1) {
        int u = (t >= off) ? tmp[t - off] : 0;
        __syncthreads();
        tmp[t] += u;
        __syncthreads();
    }
    if (t < SCAN_NBLK) blockoff[t] = tmp[t] - v;
}

__global__ void scan3_kernel(int* __restrict__ row_ptr, const int* __restrict__ blockoff,
                             int* __restrict__ cursor) {
    int i = blockIdx.x * blockDim.x + threadIdx.x;
    if (i >= NN) return;
    int r = row_ptr[i] + blockoff[i >> 8];
    row_ptr[i] = r;
    cursor[i] = r;
    if (i == 0) row_ptr[NN] = NE;
}

__global__ void scatter_kernel(const int* __restrict__ srcs, const int* __restrict__ dsts,
                               int* __restrict__ cursor, int* __restrict__ csr_src) {
    int e = blockIdx.x * blockDim.x + threadIdx.x;
    if (e >= NE) return;
    int i = dsts[e];
    int pos = atomicAdd(&cursor[i], 1);
    csr_src[pos] = srcs[e];
}

// ---------------------------------------------------------------------------
// dtype conversion
// ---------------------------------------------------------------------------
__global__ void cvt_x_kernel(const float* __restrict__ x, ushort_t* __restrict__ xb) {
    int i = blockIdx.x * blockDim.x + threadIdx.x;
    if (i >= NN * DD / 8) return;
    const float* p = x + (size_t)i * 8;
    s16x8 o;
#pragma unroll
    for (int j = 0; j < 8; ++j) o[j] = (short)f2bf(p[j]);
    *(s16x8*)&xb[(size_t)i * 8] = o;
}

__global__ void cvt_w_kernel(const float* __restrict__ Wk, const float* __restrict__ Wq,
                             const float* __restrict__ Wv, const float* __restrict__ Ws,
                             ushort_t* __restrict__ wall) {
    int g = blockIdx.x * blockDim.x + threadIdx.x;
    if (g >= NL * 4 * DD * DD / 8) return;
    size_t flat = (size_t)g * 8;
    int l = (int)(flat / (4 * DD * DD));
    int r = (int)(flat % (4 * DD * DD));
    int m = r / (DD * DD);
    int o = r % (DD * DD);
    const float* src;
    switch (m) {
        case 0: src = Wk; break;
        case 1: src = Wq; break;
        case 2: src = Wv; break;
        default: src = Ws; break;
    }
    const float* p = src + (size_t)l * DD * DD + o;
    s16x8 ov;
#pragma unroll
    for (int j = 0; j < 8; ++j) ov[j] = (short)f2bf(p[j]);
    *(s16x8*)&wall[flat] = ov;
}

// ---------------------------------------------------------------------------
// MFMA 4-way GEMM. Output record per node (ushort offsets within 512):
//   [0..127] k' = -log2e*(k+bk)  (sigmoid-folded)
//   [128..383] q',v interleaved: q'_d at 128+2d, v_d at 129+2d
//   [384..511] s (skip)
// ---------------------------------------------------------------------------
__global__ __launch_bounds__(256) void gemm4_mfma(
    const ushort_t* __restrict__ xb,
    const ushort_t* __restrict__ wall,
    const float* __restrict__ bk, const float* __restrict__ bq,
    const float* __restrict__ bv,
    ushort_t* __restrict__ y,
    int layer) {
    __shared__ ushort_t wlds[DD * DD];

    const int t = threadIdx.x;
    const int w = t >> 6;
    const int lane = t & 63;
    const int row0 = blockIdx.x * 64;

    const int arow = row0 + w * 16 + (lane & 15);
    const ushort_t* ap = xb + (size_t)arow * DD + ((lane >> 4) << 3);
    s16x8 afrag[4];
#pragma unroll
    for (int kb = 0; kb < 4; ++kb) afrag[kb] = *(const s16x8*)(ap + kb * 32);

    const int dlow = lane & 15;
    const int dbase = dlow * 256;
    const int swz = (lane & 7) << 4;
    const int g16 = (lane >> 4) << 4;

    unsigned int qs[8][2];

    for (int m = 0; m < 4; ++m) {
        if (m) __syncthreads();
        const ushort_t* wsrc = wall + (((size_t)layer * 4 + m) << 14);
#pragma unroll
        for (int p = 0; p < 8; ++p) {
            int g = p * 256 + t;
            int d = g >> 4;
            int s = g & 15;
            int byteoff = d * 256 + ((s * 16) ^ ((d & 7) << 4));
            *(s16x8*)((char*)wlds + byteoff) = *(const s16x8*)(wsrc + (size_t)g * 8);
        }
        __syncthreads();

        f32x4 acc[8];
#pragma unroll
        for (int ct = 0; ct < 8; ++ct) acc[ct] = (f32x4){0.f, 0.f, 0.f, 0.f};

#pragma unroll
        for (int kb = 0; kb < 4; ++kb) {
#pragma unroll
            for (int ct = 0; ct < 8; ++ct) {
                s16x8 bfrag = *(const s16x8*)((char*)wlds + ct * 4096 + dbase +
                                              ((kb * 64 + g16) ^ swz));
                acc[ct] = __builtin_amdgcn_mfma_f32_16x16x32_bf16(afrag[kb], bfrag,
                                                                  acc[ct], 0, 0, 0);
            }
        }

        const int rbase = row0 + w * 16 + ((lane >> 4) << 2);
#pragma unroll
        for (int ct = 0; ct < 8; ++ct) {
            int c0 = ct * 16 + dlow;
            if (m == 0) {
                float bval = bk[layer * DD + c0];
#pragma unroll
                for (int j = 0; j < 4; ++j)
                    y[(size_t)(rbase + j) * 512 + c0] = f2bf((acc[ct][j] + bval) * NEG_LOG2E);
            } else if (m == 1) {
                float bval = bq[layer * DD + c0];
                qs[ct][0] = (unsigned int)f2bf((acc[ct][0] + bval) * NEG_LOG2E) |
                            ((unsigned int)f2bf((acc[ct][1] + bval) * NEG_LOG2E) << 16);
                qs[ct][1] = (unsigned int)f2bf((acc[ct][2] + bval) * NEG_LOG2E) |
                            ((unsigned int)f2bf((acc[ct][3] + bval) * NEG_LOG2E) << 16);
            } else if (m == 2) {
                float bval = bv[layer * DD + c0];
#pragma unroll
                for (int j = 0; j < 4; ++j) {
                    unsigned int q16 = (qs[ct][j >> 1] >> ((j & 1) * 16)) & 0xFFFFu;
                    unsigned int val = q16 | ((unsigned int)f2bf(acc[ct][j] + bval) << 16);
                    *(unsigned int*)&y[(size_t)(rbase + j) * 512 + 128 + 2 * c0] = val;
                }
            } else {
#pragma unroll
                for (int j = 0; j < 4; ++j)
                    y[(size_t)(rbase + j) * 512 + 384 + c0] = f2bf(acc[ct][j]);
            }
        }
    }
}

// ---------------------------------------------------------------------------
// Aggregation + fused epilogue. One wave per node (wid forced to SGPR so
// row_ptr/csr_src go through scalar loads); lane owns dims 2l,2l+1.
// Edge loop unrolled x8 (8 independent 8B gathers in flight).
// gate = rcp(1 + exp2(k' + q')) with the -log2e factor pre-folded into k,q.
// ---------------------------------------------------------------------------
__global__ __launch_bounds__(256) void agg_kernel(
    const float* __restrict__ hin,
    const ushort_t* __restrict__ kqvs,   // [N][512] bf16 (k' | q'v | s)
    const int* __restrict__ row_ptr,
    const int* __restrict__ csr_src,
    const float* __restrict__ gamma, const float* __restrict__ beta,
    float* __restrict__ hout, ushort_t* __restrict__ xb_next,
    int layer, int final_norm) {
    int wid = __builtin_amdgcn_readfirstlane(
        (int)((blockIdx.x * blockDim.x + threadIdx.x) >> 6));
    if (wid >= NN) return;
    int lane = threadIdx.x & 63;
    int d0 = lane * 2;

    const ushort_t* base_i = kqvs + ((unsigned)wid << 9);
    ushort2 kraw = *(const ushort2*)&base_i[d0];
    ushort2 sraw = *(const ushort2*)&base_i[384 + d0];
    float kx = bf2f(kraw.x), ky = bf2f(kraw.y);   // pre-scaled by -log2e
    float ax = bf2f(sraw.x), ay = bf2f(sraw.y);

    const unsigned qvoff = 128u + 4u * (unsigned)lane;  // ushort offset in record
    int s = row_ptr[wid];
    int e = row_ptr[wid + 1];
    int idx = s;

#define GATE(wrd, KK, AA)                                                    \
    do {                                                                     \
        float qf = __uint_as_float((wrd) << 16);                             \
        float vf = __uint_as_float((wrd) & 0xFFFF0000u);                     \
        float g = __builtin_amdgcn_rcpf(1.0f +                               \
                    __builtin_amdgcn_exp2f(KK + qf));                        \
        AA += g * vf;                                                        \
    } while (0)

    while (idx + 8 <= e) {
        uint2 wv[8];
#pragma unroll
        for (int u = 0; u < 8; ++u) {
            unsigned off = ((unsigned)csr_src[idx + u] << 9) + qvoff;
            wv[u] = *(const uint2*)&kqvs[off];
        }
#pragma unroll
        for (int u = 0; u < 8; ++u) {
            GATE(wv[u].x, kx, ax);
            GATE(wv[u].y, ky, ay);
        }
        idx += 8;
    }
    while (idx + 2 <= e) {
        uint2 w0, w1;
        {
            unsigned off0 = ((unsigned)csr_src[idx] << 9) + qvoff;
            unsigned off1 = ((unsigned)csr_src[idx + 1] << 9) + qvoff;
            w0 = *(const uint2*)&kqvs[off0];
            w1 = *(const uint2*)&kqvs[off1];
        }
        GATE(w0.x, kx, ax);
        GATE(w0.y, ky, ay);
        GATE(w1.x, kx, ax);
        GATE(w1.y, ky, ay);
        idx += 2;
    }
    if (idx < e) {
        unsigned off = ((unsigned)csr_src[idx] << 9) + qvoff;
        uint2 w0 = *(const uint2*)&kqvs[off];
        GATE(w0.x, kx, ax);
        GATE(w0.y, ky, ay);
    }
#undef GATE

    float gx = gamma[layer * DD + d0], gy = gamma[layer * DD + d0 + 1];
    float btx = beta[layer * DD + d0], bty = beta[layer * DD + d0 + 1];
    float rx = fmaxf(ax * gx + btx, 0.f);
    float ry = fmaxf(ay * gy + bty, 0.f);

    float ss = rx * rx + ry * ry;
#pragma unroll
    for (int m = 1; m < 64; m <<= 1) ss += __shfl_xor(ss, m);
    float inv = __builtin_amdgcn_rcpf(fmaxf(sqrtf(ss), 1e-12f));

    float2 xin = *(const float2*)&hin[(size_t)wid * DD + d0];
    float hx = xin.x + rx * inv;
    float hy = xin.y + ry * inv;

    if (final_norm) {
        float s2 = hx * hx + hy * hy;
#pragma unroll
        for (int m = 1; m < 64; m <<= 1) s2 += __shfl_xor(s2, m);
        float inv2 = __builtin_amdgcn_rcpf(fmaxf(sqrtf(s2), 1e-12f));
        hx *= inv2;
        hy *= inv2;
    }
    float2 o;
    o.x = hx;
    o.y = hy;
    *(float2*)&hout[(size_t)wid * DD + d0] = o;
    if (xb_next) {
        ushort2 ob;
        ob.x = f2bf(hx);
        ob.y = f2bf(hy);
        *(ushort2*)&xb_next[(size_t)wid * DD + d0] = ob;
    }
}

// ---------------------------------------------------------------------------
extern "C" void kernel_launch(void* const* d_in, const int* in_sizes, int n_in,
                              void* d_out, int out_size, void* d_ws, size_t ws_size,
                              hipStream_t stream) {
    const float* x     = (const float*)d_in[0];
    const int*   ei    = (const int*)d_in[1];
    const float* Wk    = (const float*)d_in[2];
    const float* bk    = (const float*)d_in[3];
    const float* Wq    = (const float*)d_in[4];
    const float* bq    = (const float*)d_in[5];
    const float* Wv    = (const float*)d_in[6];
    const float* bv    = (const float*)d_in[7];
    const float* Ws    = (const float*)d_in[8];
    const float* gamma = (const float*)d_in[9];
    const float* beta  = (const float*)d_in[10];
    float* out = (float*)d_out;

    float* hb0 = (float*)d_ws;
    float* hb1 = hb0 + (size_t)NN * DD;
    ushort_t* kqvs = (ushort_t*)(hb1 + (size_t)NN * DD);
    ushort_t* xb   = kqvs + (size_t)NN * 4 * DD;
    ushort_t* wall = xb + (size_t)NN * DD;
    int* srcs     = (int*)(wall + (size_t)NL * 4 * DD * DD);
    int* dsts     = srcs + NE;
    int* count    = dsts + NE;
    int* cursor   = count + NN;
    int* row_ptr  = cursor + NN;
    int* csr_src  = row_ptr + (NN + 1);
    int* blocksum = csr_src + NE;
    int* blockoff = blocksum + SCAN_NBLK;

    hipMemsetAsync(count, 0, NN * sizeof(int), stream);
    convert_hist_kernel<<<(NE + 255) / 256, 256, 0, stream>>>(ei, srcs, dsts, count);
    scan1_kernel<<<SCAN_NBLK, 256, 0, stream>>>(count, row_ptr, blocksum);
    scan2_kernel<<<1, 256, 0, stream>>>(blocksum, blockoff);
    scan3_kernel<<<(NN + 255) / 256, 256, 0, stream>>>(row_ptr, blockoff, cursor);
    scatter_kernel<<<(NE + 255) / 256, 256, 0, stream>>>(srcs, dsts, cursor, csr_src);

    cvt_x_kernel<<<(NN * DD / 8 + 255) / 256, 256, 0, stream>>>(x, xb);
    cvt_w_kernel<<<(NL * 4 * DD * DD / 8 + 255) / 256, 256, 0, stream>>>(Wk, Wq, Wv, Ws, wall);

    for (int l = 0; l < NL; ++l) {
        const float* hin = (l == 0) ? x : (l == 1 ? hb0 : hb1);
        float* hout = (l == 2) ? out : (l == 0 ? hb0 : hb1);
        ushort_t* xb_next = (l == 2) ? nullptr : xb;
        gemm4_mfma<<<NN / 64, 256, 0, stream>>>(xb, wall, bk, bq, bv, kqvs, l);
        agg_kernel<<<(NN * 64) / 256, 256, 0, stream>>>(hin, kqvs, row_ptr, csr_src, gamma,
                                                        beta, hout, xb_next, l,
                                                        (l == NL - 1) ? 1 : 0);
    }
}